// Round 2
// baseline (1460.190 us; speedup 1.0000x reference)
//
#include <hip/hip_runtime.h>
#include <hip/hip_bf16.h>
#include <math.h>

#define N_NODES 50000
#define N_EDGES 1600000
// layer0: in 1433, H0=8, D0=8 ; layer1: in 64, H1=1, D1=7

// ---------------------------------------------------------------- CSR build
__global__ __launch_bounds__(256) void hist_kernel(const int* __restrict__ dst,
                                                   int* __restrict__ deg, int E) {
    int i = blockIdx.x * 256 + threadIdx.x;
    if (i < E) atomicAdd(&deg[dst[i]], 1);
}

// single-block exclusive scan over n counters -> row_start[0..n], cursor copy
__global__ __launch_bounds__(1024) void scan_kernel(const int* __restrict__ deg,
                                                    int* __restrict__ row_start,
                                                    int* __restrict__ cursor, int n) {
    __shared__ int sm[1024];
    __shared__ int sbase;
    if (threadIdx.x == 0) sbase = 0;
    __syncthreads();
    for (int start = 0; start < n; start += 1024) {
        int i = start + (int)threadIdx.x;
        int v = (i < n) ? deg[i] : 0;
        sm[threadIdx.x] = v;
        __syncthreads();
        #pragma unroll
        for (int off = 1; off < 1024; off <<= 1) {
            int t = (threadIdx.x >= (unsigned)off) ? sm[threadIdx.x - off] : 0;
            __syncthreads();
            sm[threadIdx.x] += t;
            __syncthreads();
        }
        int incl = sm[threadIdx.x];
        int excl = incl - v;
        int base = sbase;
        if (i < n) { row_start[i] = base + excl; cursor[i] = base + excl; }
        __syncthreads();
        if (threadIdx.x == 1023) sbase = base + incl;
        __syncthreads();
    }
    if (threadIdx.x == 0) row_start[n] = sbase;
}

__global__ __launch_bounds__(256) void scatter_kernel(const int* __restrict__ src,
                                                      const int* __restrict__ dst,
                                                      int* __restrict__ cursor,
                                                      int* __restrict__ csr_src, int E) {
    int i = blockIdx.x * 256 + threadIdx.x;
    if (i < E) {
        int p = atomicAdd(&cursor[dst[i]], 1);
        csr_src[p] = src[i];
    }
}

// ---------------------------------------------------------------- GEMM0: [M,K]x[K,64]
#define GBM 64
#define GBK 32
__global__ __launch_bounds__(256) void gemm0_kernel(const float* __restrict__ A,
                                                    const float* __restrict__ B,
                                                    float* __restrict__ C, int M, int K) {
    __shared__ __align__(16) float As[GBK][GBM + 4];   // [32][68] transposed tile
    __shared__ __align__(16) float Bs[GBK][64];
    int tid = threadIdx.x;
    int bm = blockIdx.x * GBM;
    int tm = tid >> 4;   // 0..15
    int tn = tid & 15;   // 0..15
    float acc[4][4] = {};
    for (int k0 = 0; k0 < K; k0 += GBK) {
        #pragma unroll
        for (int i = 0; i < 8; ++i) {          // 64x32 A tile, 8 elems/thread
            int e = tid + 256 * i;
            int r = e >> 5, c = e & 31;
            int gr = bm + r, gc = k0 + c;
            As[c][r] = (gr < M && gc < K) ? A[gr * K + gc] : 0.f;
        }
        #pragma unroll
        for (int i = 0; i < 8; ++i) {          // 32x64 B tile
            int e = tid + 256 * i;
            int rk = e >> 6, c = e & 63;
            int gk = k0 + rk;
            Bs[rk][c] = (gk < K) ? B[gk * 64 + c] : 0.f;
        }
        __syncthreads();
        #pragma unroll
        for (int k = 0; k < GBK; ++k) {
            float4 a4 = *(const float4*)&As[k][tm * 4];
            float4 b4 = *(const float4*)&Bs[k][tn * 4];
            acc[0][0] += a4.x * b4.x; acc[0][1] += a4.x * b4.y; acc[0][2] += a4.x * b4.z; acc[0][3] += a4.x * b4.w;
            acc[1][0] += a4.y * b4.x; acc[1][1] += a4.y * b4.y; acc[1][2] += a4.y * b4.z; acc[1][3] += a4.y * b4.w;
            acc[2][0] += a4.z * b4.x; acc[2][1] += a4.z * b4.y; acc[2][2] += a4.z * b4.z; acc[2][3] += a4.z * b4.w;
            acc[3][0] += a4.w * b4.x; acc[3][1] += a4.w * b4.y; acc[3][2] += a4.w * b4.z; acc[3][3] += a4.w * b4.w;
        }
        __syncthreads();
    }
    #pragma unroll
    for (int j = 0; j < 4; ++j) {
        int gr = bm + tm * 4 + j;
        if (gr < M)
            *(float4*)&C[gr * 64 + tn * 4] = make_float4(acc[j][0], acc[j][1], acc[j][2], acc[j][3]);
    }
}

// ---------------------------------------------------------------- el0/er0
__global__ __launch_bounds__(256) void eler0_kernel(const float* __restrict__ h0,
                                                    const float* __restrict__ al0,
                                                    const float* __restrict__ ar0,
                                                    float* __restrict__ el0,
                                                    float* __restrict__ er0, int n) {
    int idx = blockIdx.x * 256 + threadIdx.x;
    if (idx >= n * 8) return;
    int nd = idx >> 3, h = idx & 7;
    const float* hp = h0 + nd * 64 + h * 8;
    float el = 0.f, er = 0.f;
    #pragma unroll
    for (int d = 0; d < 8; ++d) {
        float v = hp[d];
        el += v * al0[h * 8 + d];
        er += v * ar0[h * 8 + d];
    }
    el0[idx] = el;
    er0[idx] = er;
}

// ---------------------------------------------------------------- layer0 aggregation
// one wave per node; lane = head*8 + dim; online softmax; fused GEMM1 epilogue
__global__ __launch_bounds__(256) void agg0_kernel(const int* __restrict__ row_start,
                                                   const int* __restrict__ csr_src,
                                                   const float* __restrict__ h0,
                                                   const float* __restrict__ el0,
                                                   const float* __restrict__ er0,
                                                   const float* __restrict__ W1,
                                                   const float* __restrict__ al1,
                                                   const float* __restrict__ ar1,
                                                   float* __restrict__ h1,
                                                   float* __restrict__ el1,
                                                   float* __restrict__ er1, int n_nodes) {
    int wid = blockIdx.x * 4 + (threadIdx.x >> 6);
    if (wid >= n_nodes) return;
    int lane = threadIdx.x & 63;
    int h = lane >> 3;
    float er_h = er0[wid * 8 + h];
    int rs = row_start[wid], re = row_start[wid + 1];
    float m = -INFINITY, den = 0.f, acc = 0.f;
    for (int i = rs; i < re; ++i) {
        int s = csr_src[i];
        float e = el0[s * 8 + h] + er_h;
        e = (e >= 0.f) ? e : 0.2f * e;          // leaky_relu
        float hv = h0[s * 64 + lane];
        float mn = fmaxf(m, e);
        float sc = __expf(m - mn);              // m=-inf first iter -> 0
        float p  = __expf(e - mn);
        den = den * sc + p;
        acc = acc * sc + p * hv;
        m = mn;
    }
    float val = (re > rs) ? acc / den : 0.f;
    float z = (val > 0.f) ? val : expm1f(val);  // ELU
    // fused GEMM1: h1[wid][j] = sum_k z_k * W1[k][j], k = lane
    float r[7];
    #pragma unroll
    for (int j = 0; j < 7; ++j) r[j] = z * W1[lane * 7 + j];
    #pragma unroll
    for (int off = 1; off < 64; off <<= 1) {
        #pragma unroll
        for (int j = 0; j < 7; ++j) r[j] += __shfl_xor(r[j], off, 64);
    }
    if (lane == 0) {
        float el = 0.f, er = 0.f;
        #pragma unroll
        for (int j = 0; j < 7; ++j) {
            el += r[j] * al1[j];
            er += r[j] * ar1[j];
            h1[wid * 7 + j] = r[j];
        }
        el1[wid] = el;
        er1[wid] = er;
    }
}

// ---------------------------------------------------------------- layer1 aggregation
// one wave per node; lanes parallel over edges; two-pass softmax
__global__ __launch_bounds__(256) void agg1_kernel(const int* __restrict__ row_start,
                                                   const int* __restrict__ csr_src,
                                                   const float* __restrict__ h1,
                                                   const float* __restrict__ el1,
                                                   const float* __restrict__ er1,
                                                   float* __restrict__ out, int n_nodes) {
    int wid = blockIdx.x * 4 + (threadIdx.x >> 6);
    if (wid >= n_nodes) return;
    int lane = threadIdx.x & 63;
    int rs = row_start[wid], re = row_start[wid + 1];
    float ern = er1[wid];
    float m = -INFINITY;
    for (int base = rs; base < re; base += 64) {
        int i = base + lane;
        if (i < re) {
            float e = el1[csr_src[i]] + ern;
            e = (e >= 0.f) ? e : 0.2f * e;
            m = fmaxf(m, e);
        }
    }
    #pragma unroll
    for (int off = 1; off < 64; off <<= 1) m = fmaxf(m, __shfl_xor(m, off, 64));
    float den = 0.f;
    float acc[7] = {0.f, 0.f, 0.f, 0.f, 0.f, 0.f, 0.f};
    for (int base = rs; base < re; base += 64) {
        int i = base + lane;
        if (i < re) {
            int s = csr_src[i];
            float e = el1[s] + ern;
            e = (e >= 0.f) ? e : 0.2f * e;
            float p = __expf(e - m);
            den += p;
            #pragma unroll
            for (int d = 0; d < 7; ++d) acc[d] += p * h1[s * 7 + d];
        }
    }
    #pragma unroll
    for (int off = 1; off < 64; off <<= 1) {
        den += __shfl_xor(den, off, 64);
        #pragma unroll
        for (int d = 0; d < 7; ++d) acc[d] += __shfl_xor(acc[d], off, 64);
    }
    if (lane == 0) {
        float inv = (re > rs) ? 1.f / den : 0.f;
        #pragma unroll
        for (int d = 0; d < 7; ++d) out[wid * 7 + d] = acc[d] * inv;
    }
}

// ---------------------------------------------------------------- launch
extern "C" void kernel_launch(void* const* d_in, const int* in_sizes, int n_in,
                              void* d_out, int out_size, void* d_ws, size_t ws_size,
                              hipStream_t stream) {
    const float* feat = (const float*)d_in[0];
    const int*   src  = (const int*)d_in[1];
    const int*   dst  = (const int*)d_in[2];
    const float* W0   = (const float*)d_in[3];
    const float* al0  = (const float*)d_in[4];
    const float* ar0  = (const float*)d_in[5];
    const float* W1   = (const float*)d_in[6];
    const float* al1  = (const float*)d_in[7];
    const float* ar1  = (const float*)d_in[8];
    float* out = (float*)d_out;

    const int N = N_NODES, E = N_EDGES, K = 1433;

    // workspace layout (~25 MB total; harness re-poisons to 0xAA each call,
    // every buffer below is fully rewritten every call)
    char* w = (char*)d_ws;
    size_t off = 0;
    auto get = [&](size_t bytes) {
        char* p = w + off;
        off += (bytes + 255) & ~(size_t)255;
        return p;
    };
    int*   deg       = (int*)get((size_t)N * 4);
    int*   row_start = (int*)get((size_t)(N + 1) * 4);
    int*   cursor    = (int*)get((size_t)N * 4);
    int*   csr_src   = (int*)get((size_t)E * 4);
    float* h0        = (float*)get((size_t)N * 64 * 4);
    float* el0       = (float*)get((size_t)N * 8 * 4);
    float* er0       = (float*)get((size_t)N * 8 * 4);
    float* h1        = (float*)get((size_t)N * 7 * 4);
    float* el1       = (float*)get((size_t)N * 4);
    float* er1       = (float*)get((size_t)N * 4);

    hipMemsetAsync(deg, 0, (size_t)N * 4, stream);
    hist_kernel<<<(E + 255) / 256, 256, 0, stream>>>(dst, deg, E);
    scan_kernel<<<1, 1024, 0, stream>>>(deg, row_start, cursor, N);
    scatter_kernel<<<(E + 255) / 256, 256, 0, stream>>>(src, dst, cursor, csr_src, E);

    gemm0_kernel<<<(N + GBM - 1) / GBM, 256, 0, stream>>>(feat, W0, h0, N, K);
    eler0_kernel<<<(N * 8 + 255) / 256, 256, 0, stream>>>(h0, al0, ar0, el0, er0, N);

    agg0_kernel<<<(N + 3) / 4, 256, 0, stream>>>(row_start, csr_src, h0, el0, er0,
                                                 W1, al1, ar1, h1, el1, er1, N);
    agg1_kernel<<<(N + 3) / 4, 256, 0, stream>>>(row_start, csr_src, h1, el1, er1, out, N);
}

// Round 5
// 1009.798 us; speedup vs baseline: 1.4460x; 1.4460x over previous
//
#include <hip/hip_runtime.h>
#include <hip/hip_bf16.h>
#include <math.h>

#define N_NODES 50000
#define N_EDGES 1600000
// layer0: in 1433, H0=8, D0=8 ; layer1: in 64, H1=1, D1=7

// ---------------------------------------------------------------- CSR build
__global__ __launch_bounds__(256) void hist_kernel(const int* __restrict__ dst,
                                                   int* __restrict__ deg, int E) {
    int i = blockIdx.x * 256 + threadIdx.x;
    if (i < E) atomicAdd(&deg[dst[i]], 1);
}

// multi-block scan, stage 1: per-block inclusive scan -> exclusive local + block sums
__global__ __launch_bounds__(1024) void scan1_kernel(const int* __restrict__ deg,
                                                     int* __restrict__ excl,
                                                     int* __restrict__ bsum, int n) {
    __shared__ int sm[1024];
    int tid = threadIdx.x;
    int i = blockIdx.x * 1024 + tid;
    int v = (i < n) ? deg[i] : 0;
    sm[tid] = v;
    __syncthreads();
    #pragma unroll
    for (int off = 1; off < 1024; off <<= 1) {
        int t = (tid >= off) ? sm[tid - off] : 0;
        __syncthreads();
        sm[tid] += t;
        __syncthreads();
    }
    if (i < n) excl[i] = sm[tid] - v;
    if (tid == 1023) bsum[blockIdx.x] = sm[1023];
}

// stage 2: single wave scans block sums (nb <= 64)
__global__ __launch_bounds__(64) void scan2_kernel(const int* __restrict__ bsum,
                                                   int* __restrict__ boff, int nb) {
    int lane = threadIdx.x;
    int s = (lane < nb) ? bsum[lane] : 0;
    int v = s;
    #pragma unroll
    for (int off = 1; off < 64; off <<= 1) {
        int t = __shfl_up(v, off, 64);
        if (lane >= off) v += t;
    }
    if (lane < nb) boff[lane] = v - s;     // exclusive
    if (lane == 63) boff[nb] = v;          // grand total
}

// stage 3: apply block offsets -> row_start + cursor
__global__ __launch_bounds__(1024) void scan3_kernel(const int* __restrict__ excl,
                                                     const int* __restrict__ boff,
                                                     int* __restrict__ row_start,
                                                     int* __restrict__ cursor, int n, int nb) {
    int i = blockIdx.x * 1024 + threadIdx.x;
    if (i < n) {
        int rs = excl[i] + boff[i >> 10];
        row_start[i] = rs;
        cursor[i] = rs;
    }
    if (i == 0) row_start[n] = boff[nb];
}

__global__ __launch_bounds__(256) void scatter_kernel(const int* __restrict__ src,
                                                      const int* __restrict__ dst,
                                                      int* __restrict__ cursor,
                                                      int* __restrict__ csr_src, int E) {
    int i = blockIdx.x * 256 + threadIdx.x;
    if (i < E) {
        int p = atomicAdd(&cursor[dst[i]], 1);
        csr_src[p] = src[i];
    }
}

// ---------------------------------------------------------------- GEMM0: [M,K]x[K,64]
// 64x64 tile, BK=32, 256 threads, 4x4 reg tile, double-buffered LDS (reg-staged).
__global__ __launch_bounds__(256) void gemm0_kernel(const float* __restrict__ A,
                                                    const float* __restrict__ B,
                                                    float* __restrict__ C, int M, int K) {
    // As transposed [k][row], pad 68 (16B-aligned stride, reads hit 4 distinct banks)
    __shared__ __align__(16) float As[2][32][68];
    __shared__ __align__(16) float Bs[2][32][64];
    int tid = threadIdx.x;
    int bm = blockIdx.x * 64;
    int tm = tid >> 4;    // 0..15 -> row group *4
    int tn = tid & 15;    // 0..15 -> col group *4

    float ar[8];          // A staging: e=tid+256i -> r=e>>5, c=e&31
    float4 br[2];         // B staging: rk=(tid>>4)+16j, c4=(tid&15)*4

    auto load_tile = [&](int k0) {
        #pragma unroll
        for (int i = 0; i < 8; ++i) {
            int e = tid + 256 * i;
            int r = e >> 5, c = e & 31;
            int gr = bm + r, gc = k0 + c;
            ar[i] = (gr < M && gc < K) ? A[(size_t)gr * K + gc] : 0.f;
        }
        #pragma unroll
        for (int j = 0; j < 2; ++j) {
            int rk = (tid >> 4) + 16 * j;
            int gk = k0 + rk;
            br[j] = (gk < K) ? *(const float4*)&B[gk * 64 + (tid & 15) * 4]
                             : make_float4(0.f, 0.f, 0.f, 0.f);
        }
    };
    auto store_tile = [&](int buf) {
        #pragma unroll
        for (int i = 0; i < 8; ++i) {
            int e = tid + 256 * i;
            int r = e >> 5, c = e & 31;
            As[buf][c][r] = ar[i];
        }
        #pragma unroll
        for (int j = 0; j < 2; ++j) {
            int rk = (tid >> 4) + 16 * j;
            *(float4*)&Bs[buf][rk][(tid & 15) * 4] = br[j];
        }
    };

    float acc[4][4] = {};
    int nt = (K + 31) / 32;   // 45
    load_tile(0);
    store_tile(0);
    __syncthreads();
    for (int t = 0; t < nt; ++t) {
        int cur = t & 1;
        if (t + 1 < nt) load_tile((t + 1) * 32);   // issue next-tile global loads
        #pragma unroll
        for (int k = 0; k < 32; ++k) {
            float4 a4 = *(const float4*)&As[cur][k][tm * 4];
            float4 b4 = *(const float4*)&Bs[cur][k][tn * 4];
            acc[0][0] += a4.x * b4.x; acc[0][1] += a4.x * b4.y; acc[0][2] += a4.x * b4.z; acc[0][3] += a4.x * b4.w;
            acc[1][0] += a4.y * b4.x; acc[1][1] += a4.y * b4.y; acc[1][2] += a4.y * b4.z; acc[1][3] += a4.y * b4.w;
            acc[2][0] += a4.z * b4.x; acc[2][1] += a4.z * b4.y; acc[2][2] += a4.z * b4.z; acc[2][3] += a4.z * b4.w;
            acc[3][0] += a4.w * b4.x; acc[3][1] += a4.w * b4.y; acc[3][2] += a4.w * b4.z; acc[3][3] += a4.w * b4.w;
        }
        if (t + 1 < nt) store_tile((t + 1) & 1);   // write to the other buffer (safe: its readers finished last iter)
        __syncthreads();
    }
    #pragma unroll
    for (int j = 0; j < 4; ++j) {
        int gr = bm + tm * 4 + j;
        if (gr < M)
            *(float4*)&C[gr * 64 + tn * 4] = make_float4(acc[j][0], acc[j][1], acc[j][2], acc[j][3]);
    }
}

// ---------------------------------------------------------------- el0/er0
__global__ __launch_bounds__(256) void eler0_kernel(const float* __restrict__ h0,
                                                    const float* __restrict__ al0,
                                                    const float* __restrict__ ar0,
                                                    float* __restrict__ el0,
                                                    float* __restrict__ er0, int n) {
    int idx = blockIdx.x * 256 + threadIdx.x;
    if (idx >= n * 8) return;
    int nd = idx >> 3, h = idx & 7;
    const float* hp = h0 + nd * 64 + h * 8;
    float el = 0.f, er = 0.f;
    #pragma unroll
    for (int d = 0; d < 8; ++d) {
        float v = hp[d];
        el += v * al0[h * 8 + d];
        er += v * ar0[h * 8 + d];
    }
    el0[idx] = el;
    er0[idx] = er;
}

// ---------------------------------------------------------------- layer0 aggregation
// one wave per node; lane = head*8 + dim; online softmax; fused GEMM1 epilogue
__global__ __launch_bounds__(256) void agg0_kernel(const int* __restrict__ row_start,
                                                   const int* __restrict__ csr_src,
                                                   const float* __restrict__ h0,
                                                   const float* __restrict__ el0,
                                                   const float* __restrict__ er0,
                                                   const float* __restrict__ W1,
                                                   const float* __restrict__ al1,
                                                   const float* __restrict__ ar1,
                                                   float* __restrict__ h1,
                                                   float* __restrict__ el1,
                                                   float* __restrict__ er1, int n_nodes) {
    int wid = blockIdx.x * 4 + (threadIdx.x >> 6);
    if (wid >= n_nodes) return;
    int lane = threadIdx.x & 63;
    int h = lane >> 3;
    float er_h = er0[wid * 8 + h];
    int rs = row_start[wid], re = row_start[wid + 1];
    float m = -INFINITY, den = 0.f, acc = 0.f;
    for (int i = rs; i < re; ++i) {
        int s = csr_src[i];
        float e = el0[s * 8 + h] + er_h;
        e = (e >= 0.f) ? e : 0.2f * e;          // leaky_relu
        float hv = h0[s * 64 + lane];
        float mn = fmaxf(m, e);
        float sc = __expf(m - mn);              // m=-inf first iter -> 0
        float p  = __expf(e - mn);
        den = den * sc + p;
        acc = acc * sc + p * hv;
        m = mn;
    }
    float val = (re > rs) ? acc / den : 0.f;
    float z = (val > 0.f) ? val : expm1f(val);  // ELU
    // fused GEMM1: h1[wid][j] = sum_k z_k * W1[k][j], k = lane
    float r[7];
    #pragma unroll
    for (int j = 0; j < 7; ++j) r[j] = z * W1[lane * 7 + j];
    #pragma unroll
    for (int off = 1; off < 64; off <<= 1) {
        #pragma unroll
        for (int j = 0; j < 7; ++j) r[j] += __shfl_xor(r[j], off, 64);
    }
    if (lane == 0) {
        float el = 0.f, er = 0.f;
        #pragma unroll
        for (int j = 0; j < 7; ++j) {
            el += r[j] * al1[j];
            er += r[j] * ar1[j];
            h1[wid * 7 + j] = r[j];
        }
        el1[wid] = el;
        er1[wid] = er;
    }
}

// ---------------------------------------------------------------- layer1 aggregation
// one wave per node; lanes parallel over edges; two-pass softmax
__global__ __launch_bounds__(256) void agg1_kernel(const int* __restrict__ row_start,
                                                   const int* __restrict__ csr_src,
                                                   const float* __restrict__ h1,
                                                   const float* __restrict__ el1,
                                                   const float* __restrict__ er1,
                                                   float* __restrict__ out, int n_nodes) {
    int wid = blockIdx.x * 4 + (threadIdx.x >> 6);
    if (wid >= n_nodes) return;
    int lane = threadIdx.x & 63;
    int rs = row_start[wid], re = row_start[wid + 1];
    float ern = er1[wid];
    float m = -INFINITY;
    for (int base = rs; base < re; base += 64) {
        int i = base + lane;
        if (i < re) {
            float e = el1[csr_src[i]] + ern;
            e = (e >= 0.f) ? e : 0.2f * e;
            m = fmaxf(m, e);
        }
    }
    #pragma unroll
    for (int off = 1; off < 64; off <<= 1) m = fmaxf(m, __shfl_xor(m, off, 64));
    float den = 0.f;
    float acc[7] = {0.f, 0.f, 0.f, 0.f, 0.f, 0.f, 0.f};
    for (int base = rs; base < re; base += 64) {
        int i = base + lane;
        if (i < re) {
            int s = csr_src[i];
            float e = el1[s] + ern;
            e = (e >= 0.f) ? e : 0.2f * e;
            float p = __expf(e - m);
            den += p;
            #pragma unroll
            for (int d = 0; d < 7; ++d) acc[d] += p * h1[s * 7 + d];
        }
    }
    #pragma unroll
    for (int off = 1; off < 64; off <<= 1) {
        den += __shfl_xor(den, off, 64);
        #pragma unroll
        for (int d = 0; d < 7; ++d) acc[d] += __shfl_xor(acc[d], off, 64);
    }
    if (lane == 0) {
        float inv = (re > rs) ? 1.f / den : 0.f;
        #pragma unroll
        for (int d = 0; d < 7; ++d) out[wid * 7 + d] = acc[d] * inv;
    }
}

// ---------------------------------------------------------------- launch
extern "C" void kernel_launch(void* const* d_in, const int* in_sizes, int n_in,
                              void* d_out, int out_size, void* d_ws, size_t ws_size,
                              hipStream_t stream) {
    const float* feat = (const float*)d_in[0];
    const int*   src  = (const int*)d_in[1];
    const int*   dst  = (const int*)d_in[2];
    const float* W0   = (const float*)d_in[3];
    const float* al0  = (const float*)d_in[4];
    const float* ar0  = (const float*)d_in[5];
    const float* W1   = (const float*)d_in[6];
    const float* al1  = (const float*)d_in[7];
    const float* ar1  = (const float*)d_in[8];
    float* out = (float*)d_out;

    const int N = N_NODES, E = N_EDGES, K = 1433;
    const int NB = (N + 1023) / 1024;   // 49 scan blocks

    char* w = (char*)d_ws;
    size_t off = 0;
    auto get = [&](size_t bytes) {
        char* p = w + off;
        off += (bytes + 255) & ~(size_t)255;
        return p;
    };
    int*   deg       = (int*)get((size_t)N * 4);
    int*   row_start = (int*)get((size_t)(N + 1) * 4);
    int*   cursor    = (int*)get((size_t)N * 4);
    int*   csr_src   = (int*)get((size_t)E * 4);
    int*   excl      = (int*)get((size_t)N * 4);
    int*   bsum      = (int*)get((size_t)(NB + 1) * 4);
    int*   boff      = (int*)get((size_t)(NB + 1) * 4);
    float* h0        = (float*)get((size_t)N * 64 * 4);
    float* el0       = (float*)get((size_t)N * 8 * 4);
    float* er0       = (float*)get((size_t)N * 8 * 4);
    float* h1        = (float*)get((size_t)N * 7 * 4);
    float* el1       = (float*)get((size_t)N * 4);
    float* er1       = (float*)get((size_t)N * 4);

    hipMemsetAsync(deg, 0, (size_t)N * 4, stream);
    hist_kernel<<<(E + 255) / 256, 256, 0, stream>>>(dst, deg, E);
    scan1_kernel<<<NB, 1024, 0, stream>>>(deg, excl, bsum, N);
    scan2_kernel<<<1, 64, 0, stream>>>(bsum, boff, NB);
    scan3_kernel<<<NB, 1024, 0, stream>>>(excl, boff, row_start, cursor, N, NB);
    scatter_kernel<<<(E + 255) / 256, 256, 0, stream>>>(src, dst, cursor, csr_src, E);

    gemm0_kernel<<<(N + 63) / 64, 256, 0, stream>>>(feat, W0, h0, N, K);
    eler0_kernel<<<(N * 8 + 255) / 256, 256, 0, stream>>>(h0, al0, ar0, el0, er0, N);

    agg0_kernel<<<(N + 3) / 4, 256, 0, stream>>>(row_start, csr_src, h0, el0, er0,
                                                 W1, al1, ar1, h1, el1, er1, N);
    agg1_kernel<<<(N + 3) / 4, 256, 0, stream>>>(row_start, csr_src, h1, el1, er1, out, N);
}

// Round 6
// 834.288 us; speedup vs baseline: 1.7502x; 1.2104x over previous
//
#include <hip/hip_runtime.h>
#include <hip/hip_bf16.h>
#include <math.h>

#define N_NODES 50000
#define N_EDGES 1600000
// layer0: in 1433, H0=8, D0=8 ; layer1: in 64, H1=1, D1=7

typedef __attribute__((ext_vector_type(8))) short bf16x8;
typedef __attribute__((ext_vector_type(4))) float f32x4;

__device__ __forceinline__ unsigned short f32_to_bf16(float f) {
    unsigned u = __float_as_uint(f);
    unsigned r = u + 0x7FFFu + ((u >> 16) & 1u);   // RNE
    return (unsigned short)(r >> 16);
}
__device__ __forceinline__ float bf16_to_f32(unsigned short s) {
    return __uint_as_float(((unsigned)s) << 16);
}

// ---------------------------------------------------------------- CSR build
__global__ __launch_bounds__(256) void hist_kernel(const int* __restrict__ dst,
                                                   int* __restrict__ deg, int E) {
    int i = blockIdx.x * 256 + threadIdx.x;
    if (i < E) atomicAdd(&deg[dst[i]], 1);
}

__global__ __launch_bounds__(1024) void scan1_kernel(const int* __restrict__ deg,
                                                     int* __restrict__ excl,
                                                     int* __restrict__ bsum, int n) {
    __shared__ int sm[1024];
    int tid = threadIdx.x;
    int i = blockIdx.x * 1024 + tid;
    int v = (i < n) ? deg[i] : 0;
    sm[tid] = v;
    __syncthreads();
    #pragma unroll
    for (int off = 1; off < 1024; off <<= 1) {
        int t = (tid >= off) ? sm[tid - off] : 0;
        __syncthreads();
        sm[tid] += t;
        __syncthreads();
    }
    if (i < n) excl[i] = sm[tid] - v;
    if (tid == 1023) bsum[blockIdx.x] = sm[1023];
}

__global__ __launch_bounds__(64) void scan2_kernel(const int* __restrict__ bsum,
                                                   int* __restrict__ boff, int nb) {
    int lane = threadIdx.x;
    int s = (lane < nb) ? bsum[lane] : 0;
    int v = s;
    #pragma unroll
    for (int off = 1; off < 64; off <<= 1) {
        int t = __shfl_up(v, off, 64);
        if (lane >= off) v += t;
    }
    if (lane < nb) boff[lane] = v - s;
    if (lane == 63) boff[nb] = v;
}

__global__ __launch_bounds__(1024) void scan3_kernel(const int* __restrict__ excl,
                                                     const int* __restrict__ boff,
                                                     int* __restrict__ row_start,
                                                     int* __restrict__ cursor, int n, int nb) {
    int i = blockIdx.x * 1024 + threadIdx.x;
    if (i < n) {
        int rs = excl[i] + boff[i >> 10];
        row_start[i] = rs;
        cursor[i] = rs;
    }
    if (i == 0) row_start[n] = boff[nb];
}

__global__ __launch_bounds__(256) void scatter_kernel(const int* __restrict__ src,
                                                      const int* __restrict__ dst,
                                                      int* __restrict__ cursor,
                                                      int* __restrict__ csr_src, int E) {
    int i = blockIdx.x * 256 + threadIdx.x;
    if (i < E) {
        int p = atomicAdd(&cursor[dst[i]], 1);
        csr_src[p] = src[i];
    }
}

// ---------------------------------------------------------------- GEMM0 (MFMA bf16 hi/lo)
// C[M,64] = A[M,K] * B[K,64], fp32 in/out, internally bf16 split:
//   C = Ahi*Bhi + Alo*Bhi + Ahi*Blo   (lo*lo dropped, ~1e-4 abs)
// 64x64 tile, BK=32, 4 waves (wave w -> rows w*16..w*16+15, all 64 cols).
// LDS planes [64][32] bf16, XOR swizzle byte ^= ((row&7)<<4); double-buffered.
__global__ __launch_bounds__(256, 4) void gemm0_kernel(const float* __restrict__ A,
                                                       const float* __restrict__ B,
                                                       float* __restrict__ C, int M, int K) {
    // [buf][plane][64*32]: plane 0=A_hi 1=A_lo 2=B_hi(col-major) 3=B_lo
    __shared__ __align__(16) short smem[2][4][2048];
    const int tid  = threadIdx.x;
    const int lane = tid & 63;
    const int wave = tid >> 6;
    const int bm   = blockIdx.x * 64;

    // staging assignment
    const int ac  = tid & 31;   // A: k-col within tile (fixed per thread)
    const int ar0 = tid >> 5;   // A: base row 0..7, rows ar0+8i
    const int bcol = tid & 63;  // B: output col
    const int bkq  = tid >> 6;  // B: k-quad, k = bkq*8+j

    float areg[8], breg[8];

    auto load_tile = [&](int k0) {
        #pragma unroll
        for (int i = 0; i < 8; ++i) {
            int r = ar0 + 8 * i;
            int gr = bm + r, gc = k0 + ac;
            areg[i] = (gr < M && gc < K) ? A[(size_t)gr * K + gc] : 0.f;   // coalesced 128B/halfwave
        }
        #pragma unroll
        for (int j = 0; j < 8; ++j) {
            int gk = k0 + bkq * 8 + j;
            breg[j] = (gk < K) ? B[gk * 64 + bcol] : 0.f;                  // coalesced 256B/wave
        }
    };
    auto store_tile = [&](int buf) {
        char* base = (char*)&smem[buf][0][0];
        #pragma unroll
        for (int i = 0; i < 8; ++i) {
            int r = ar0 + 8 * i;
            int off = (r * 64 + ac * 2) ^ ((r & 7) << 4);
            float v = areg[i];
            unsigned short hi = f32_to_bf16(v);
            unsigned short lo = f32_to_bf16(v - bf16_to_f32(hi));
            *(short*)(base + off)        = (short)hi;
            *(short*)(base + 4096 + off) = (short)lo;
        }
        bf16x8 vh, vl;
        #pragma unroll
        for (int j = 0; j < 8; ++j) {
            float v = breg[j];
            unsigned short hi = f32_to_bf16(v);
            unsigned short lo = f32_to_bf16(v - bf16_to_f32(hi));
            vh[j] = (short)hi;
            vl[j] = (short)lo;
        }
        int off = (bcol * 64 + bkq * 16) ^ ((bcol & 7) << 4);   // 16B aligned
        *(bf16x8*)(base + 2 * 4096 + off) = vh;
        *(bf16x8*)(base + 3 * 4096 + off) = vl;
    };

    // fragment addresses (bytes within a plane), same swizzle as writes
    const int frow = lane & 15;
    const int kblk = lane >> 4;
    const int arow = wave * 16 + frow;
    const int a_off = (arow * 64 + kblk * 16) ^ ((arow & 7) << 4);
    int b_off[4];
    #pragma unroll
    for (int n = 0; n < 4; ++n) {
        int bc = n * 16 + frow;
        b_off[n] = (bc * 64 + kblk * 16) ^ ((bc & 7) << 4);
    }

    f32x4 acc[4] = {};
    const int nt = (K + 31) / 32;   // 45
    load_tile(0);
    store_tile(0);
    __syncthreads();
    for (int t = 0; t < nt; ++t) {
        char* base = (char*)&smem[t & 1][0][0];
        if (t + 1 < nt) load_tile((t + 1) * 32);
        bf16x8 ah = *(const bf16x8*)(base + a_off);
        bf16x8 al = *(const bf16x8*)(base + 4096 + a_off);
        #pragma unroll
        for (int n = 0; n < 4; ++n) {
            bf16x8 bh = *(const bf16x8*)(base + 2 * 4096 + b_off[n]);
            bf16x8 bl = *(const bf16x8*)(base + 3 * 4096 + b_off[n]);
            acc[n] = __builtin_amdgcn_mfma_f32_16x16x32_bf16(ah, bh, acc[n], 0, 0, 0);
            acc[n] = __builtin_amdgcn_mfma_f32_16x16x32_bf16(al, bh, acc[n], 0, 0, 0);
            acc[n] = __builtin_amdgcn_mfma_f32_16x16x32_bf16(ah, bl, acc[n], 0, 0, 0);
        }
        if (t + 1 < nt) store_tile((t + 1) & 1);   // other buffer; its readers passed last barrier
        __syncthreads();
    }
    // C/D layout (m89/m91): col = lane&15, row = (lane>>4)*4 + reg
    const int crow0 = bm + wave * 16 + (lane >> 4) * 4;
    const int ccol0 = lane & 15;
    #pragma unroll
    for (int n = 0; n < 4; ++n)
        #pragma unroll
        for (int r = 0; r < 4; ++r) {
            int gr = crow0 + r;
            if (gr < M) C[gr * 64 + n * 16 + ccol0] = acc[n][r];
        }
}

// ---------------------------------------------------------------- el0/er0
__global__ __launch_bounds__(256) void eler0_kernel(const float* __restrict__ h0,
                                                    const float* __restrict__ al0,
                                                    const float* __restrict__ ar0,
                                                    float* __restrict__ el0,
                                                    float* __restrict__ er0, int n) {
    int idx = blockIdx.x * 256 + threadIdx.x;
    if (idx >= n * 8) return;
    int nd = idx >> 3, h = idx & 7;
    const float* hp = h0 + nd * 64 + h * 8;
    float el = 0.f, er = 0.f;
    #pragma unroll
    for (int d = 0; d < 8; ++d) {
        float v = hp[d];
        el += v * al0[h * 8 + d];
        er += v * ar0[h * 8 + d];
    }
    el0[idx] = el;
    er0[idx] = er;
}

// ---------------------------------------------------------------- layer0 aggregation
__global__ __launch_bounds__(256) void agg0_kernel(const int* __restrict__ row_start,
                                                   const int* __restrict__ csr_src,
                                                   const float* __restrict__ h0,
                                                   const float* __restrict__ el0,
                                                   const float* __restrict__ er0,
                                                   const float* __restrict__ W1,
                                                   const float* __restrict__ al1,
                                                   const float* __restrict__ ar1,
                                                   float* __restrict__ h1,
                                                   float* __restrict__ el1,
                                                   float* __restrict__ er1, int n_nodes) {
    int wid = blockIdx.x * 4 + (threadIdx.x >> 6);
    if (wid >= n_nodes) return;
    int lane = threadIdx.x & 63;
    int h = lane >> 3;
    float er_h = er0[wid * 8 + h];
    int rs = row_start[wid], re = row_start[wid + 1];
    float m = -INFINITY, den = 0.f, acc = 0.f;
    for (int i = rs; i < re; ++i) {
        int s = csr_src[i];
        float e = el0[s * 8 + h] + er_h;
        e = (e >= 0.f) ? e : 0.2f * e;
        float hv = h0[s * 64 + lane];
        float mn = fmaxf(m, e);
        float sc = __expf(m - mn);
        float p  = __expf(e - mn);
        den = den * sc + p;
        acc = acc * sc + p * hv;
        m = mn;
    }
    float val = (re > rs) ? acc / den : 0.f;
    float z = (val > 0.f) ? val : expm1f(val);   // ELU
    float r[7];
    #pragma unroll
    for (int j = 0; j < 7; ++j) r[j] = z * W1[lane * 7 + j];
    #pragma unroll
    for (int off = 1; off < 64; off <<= 1) {
        #pragma unroll
        for (int j = 0; j < 7; ++j) r[j] += __shfl_xor(r[j], off, 64);
    }
    if (lane == 0) {
        float el = 0.f, er = 0.f;
        #pragma unroll
        for (int j = 0; j < 7; ++j) {
            el += r[j] * al1[j];
            er += r[j] * ar1[j];
            h1[wid * 7 + j] = r[j];
        }
        el1[wid] = el;
        er1[wid] = er;
    }
}

// ---------------------------------------------------------------- layer1 aggregation
__global__ __launch_bounds__(256) void agg1_kernel(const int* __restrict__ row_start,
                                                   const int* __restrict__ csr_src,
                                                   const float* __restrict__ h1,
                                                   const float* __restrict__ el1,
                                                   const float* __restrict__ er1,
                                                   float* __restrict__ out, int n_nodes) {
    int wid = blockIdx.x * 4 + (threadIdx.x >> 6);
    if (wid >= n_nodes) return;
    int lane = threadIdx.x & 63;
    int rs = row_start[wid], re = row_start[wid + 1];
    float ern = er1[wid];
    float m = -INFINITY;
    for (int base = rs; base < re; base += 64) {
        int i = base + lane;
        if (i < re) {
            float e = el1[csr_src[i]] + ern;
            e = (e >= 0.f) ? e : 0.2f * e;
            m = fmaxf(m, e);
        }
    }
    #pragma unroll
    for (int off = 1; off < 64; off <<= 1) m = fmaxf(m, __shfl_xor(m, off, 64));
    float den = 0.f;
    float acc[7] = {0.f, 0.f, 0.f, 0.f, 0.f, 0.f, 0.f};
    for (int base = rs; base < re; base += 64) {
        int i = base + lane;
        if (i < re) {
            int s = csr_src[i];
            float e = el1[s] + ern;
            e = (e >= 0.f) ? e : 0.2f * e;
            float p = __expf(e - m);
            den += p;
            #pragma unroll
            for (int d = 0; d < 7; ++d) acc[d] += p * h1[s * 7 + d];
        }
    }
    #pragma unroll
    for (int off = 1; off < 64; off <<= 1) {
        den += __shfl_xor(den, off, 64);
        #pragma unroll
        for (int d = 0; d < 7; ++d) acc[d] += __shfl_xor(acc[d], off, 64);
    }
    if (lane == 0) {
        float inv = (re > rs) ? 1.f / den : 0.f;
        #pragma unroll
        for (int d = 0; d < 7; ++d) out[wid * 7 + d] = acc[d] * inv;
    }
}

// ---------------------------------------------------------------- launch
extern "C" void kernel_launch(void* const* d_in, const int* in_sizes, int n_in,
                              void* d_out, int out_size, void* d_ws, size_t ws_size,
                              hipStream_t stream) {
    const float* feat = (const float*)d_in[0];
    const int*   src  = (const int*)d_in[1];
    const int*   dst  = (const int*)d_in[2];
    const float* W0   = (const float*)d_in[3];
    const float* al0  = (const float*)d_in[4];
    const float* ar0  = (const float*)d_in[5];
    const float* W1   = (const float*)d_in[6];
    const float* al1  = (const float*)d_in[7];
    const float* ar1  = (const float*)d_in[8];
    float* out = (float*)d_out;

    const int N = N_NODES, E = N_EDGES, K = 1433;
    const int NB = (N + 1023) / 1024;   // 49

    char* w = (char*)d_ws;
    size_t off = 0;
    auto get = [&](size_t bytes) {
        char* p = w + off;
        off += (bytes + 255) & ~(size_t)255;
        return p;
    };
    int*   deg       = (int*)get((size_t)N * 4);
    int*   row_start = (int*)get((size_t)(N + 1) * 4);
    int*   cursor    = (int*)get((size_t)N * 4);
    int*   csr_src   = (int*)get((size_t)E * 4);
    int*   excl      = (int*)get((size_t)N * 4);
    int*   bsum      = (int*)get((size_t)(NB + 1) * 4);
    int*   boff      = (int*)get((size_t)(NB + 1) * 4);
    float* h0        = (float*)get((size_t)N * 64 * 4);
    float* el0       = (float*)get((size_t)N * 8 * 4);
    float* er0       = (float*)get((size_t)N * 8 * 4);
    float* h1        = (float*)get((size_t)N * 7 * 4);
    float* el1       = (float*)get((size_t)N * 4);
    float* er1       = (float*)get((size_t)N * 4);

    hipMemsetAsync(deg, 0, (size_t)N * 4, stream);
    hist_kernel<<<(E + 255) / 256, 256, 0, stream>>>(dst, deg, E);
    scan1_kernel<<<NB, 1024, 0, stream>>>(deg, excl, bsum, N);
    scan2_kernel<<<1, 64, 0, stream>>>(bsum, boff, NB);
    scan3_kernel<<<NB, 1024, 0, stream>>>(excl, boff, row_start, cursor, N, NB);
    scatter_kernel<<<(E + 255) / 256, 256, 0, stream>>>(src, dst, cursor, csr_src, E);

    gemm0_kernel<<<(N + 63) / 64, 256, 0, stream>>>(feat, W0, h0, N, K);
    eler0_kernel<<<(N * 8 + 255) / 256, 256, 0, stream>>>(h0, al0, ar0, el0, er0, N);

    agg0_kernel<<<(N + 3) / 4, 256, 0, stream>>>(row_start, csr_src, h0, el0, er0,
                                                 W1, al1, ar1, h1, el1, er1, N);
    agg1_kernel<<<(N + 3) / 4, 256, 0, stream>>>(row_start, csr_src, h1, el1, er1, out, N);
}